// Round 7
// baseline (225.924 us; speedup 1.0000x reference)
//
#include <hip/hip_runtime.h>
#include <cstdint>

#define K_DIM 3072
#define B_DIM 8192
#define ROW_B 3072    /* bytes per i8 row */
#define ROW_U 768     /* u32 per i8 row */
#define BT    128     /* tile dim (128x128) */
#define NTT   64      /* 8192/128 tiles per dim */
#define NKT   48      /* K_DIM/64 K-tiles */

typedef __attribute__((ext_vector_type(4))) float f32x4;
typedef __attribute__((ext_vector_type(4))) int   i32x4;

#define QS     16.0f          /* quant scale: q = rn(x*16), exact mul */
#define INV_S2 0.00390625f    /* 1/256 */

__device__ __forceinline__ int q8(float f) {
    int q = __float2int_rn(f * QS);
    return max(-127, min(127, q));
}
__device__ __forceinline__ unsigned pack4(float a, float b, float c, float d) {
    return (unsigned)(q8(a) & 0xFF)
         | ((unsigned)(q8(b) & 0xFF) << 8)
         | ((unsigned)(q8(c) & 0xFF) << 16)
         | ((unsigned)(q8(d) & 0xFF) << 24);
}

// ---------- kernel 1: fused x_t write + i8 quantize (row-major) + row |x|^2 ----------
__global__ __launch_bounds__(384) void prep_kernel(const float* __restrict__ x,
                                                   const float* __restrict__ nz,
                                                   const float* __restrict__ logvar,
                                                   float* __restrict__ xt,     // may be null
                                                   unsigned int* __restrict__ xb,
                                                   float* __restrict__ xn,
                                                   float* __restrict__ se)
{
    const int row = blockIdx.x;
    const int tid = threadIdx.x;            // 384 threads: 8 consecutive floats each
    const float4* xr = (const float4*)(x + (size_t)row * K_DIM);
    float4 v0 = xr[2 * tid];
    float4 v1 = xr[2 * tid + 1];
    float s = v0.x * v0.x + v0.y * v0.y + v0.z * v0.z + v0.w * v0.w
            + v1.x * v1.x + v1.y * v1.y + v1.z * v1.z + v1.w * v1.w;

    if (xt) {   // fused x_t = x + exp(0.5*logvar)*noise
        const float4* nr = (const float4*)(nz + (size_t)row * K_DIM);
        float4 n0 = nr[2 * tid], n1 = nr[2 * tid + 1];
        const float sc = __expf(0.5f * logvar[0]);
        float4 o0, o1;
        o0.x = fmaf(sc, n0.x, v0.x); o0.y = fmaf(sc, n0.y, v0.y);
        o0.z = fmaf(sc, n0.z, v0.z); o0.w = fmaf(sc, n0.w, v0.w);
        o1.x = fmaf(sc, n1.x, v1.x); o1.y = fmaf(sc, n1.y, v1.y);
        o1.z = fmaf(sc, n1.z, v1.z); o1.w = fmaf(sc, n1.w, v1.w);
        float4* tr = (float4*)(xt + (size_t)row * K_DIM);
        tr[2 * tid] = o0;
        tr[2 * tid + 1] = o1;
    }

    unsigned int* dst = xb + (size_t)row * ROW_U + tid * 2;
    dst[0] = pack4(v0.x, v0.y, v0.z, v0.w);
    dst[1] = pack4(v1.x, v1.y, v1.z, v1.w);

#pragma unroll
    for (int d = 32; d > 0; d >>= 1) s += __shfl_down(s, d);
    __shared__ float red[6];
    if ((tid & 63) == 0) red[tid >> 6] = s;
    __syncthreads();
    if (tid == 0) {
        float t = 0.f;
#pragma unroll
        for (int i = 0; i < 6; ++i) t += red[i];
        xn[row] = t;
        se[row] = 0.f;
    }
}

struct Frags { i32x4 a[4]; i32x4 b[4]; };

// ---------- kernel 2: 128x128 triangular i8 Gram, reg-dbuf + 3-buf LDS, 3 blocks/CU ----------
__global__ __launch_bounds__(256, 3) void gram_lse_kernel(const unsigned int* __restrict__ xb,
                                                          const float* __restrict__ xn,
                                                          const float* __restrict__ logvar,
                                                          float* __restrict__ se)
{
    // per buffer: A 128x64B (8 KB) at [0], B 128x64B (8 KB) at [8192] => 48 KiB total
    __shared__ __align__(1024) unsigned char lds[3][16384];

    // decode linear block id -> triangular tile (bm <= bn)
    int rem = blockIdx.x;
    int bm = 0;
    while (rem >= NTT - bm) { rem -= NTT - bm; ++bm; }
    const int bn = bm + rem;

    const int tid  = threadIdx.x;           // 256
    const int lane = tid & 63;
    const int wave = tid >> 6;              // 4 waves: 2(M) x 2(N)
    const int wr = wave >> 1, wc = wave & 1;
    const int fc = lane >> 4;               // 16B chunk group 0..3

    const size_t rowA0 = (size_t)bm * BT;
    const size_t rowB0 = (size_t)bn * BT;
    const unsigned char* xb8 = (const unsigned char*)xb;

    // staging: 4 slots/thread/K-tile (2 A + 2 B), 16 B each.
    // slot element e -> row r=e>>2, chunk c=e&3; source chunk PRE-SWIZZLED
    // (c ^ (r>>1)&3); LDS dest linear (rule #21).
    unsigned int srcOff[4];
    int dstOff[4];
#pragma unroll
    for (int l = 0; l < 4; ++l) {
        const int e = (l & 1) * 256 + tid;
        const int r = e >> 2, c = e & 3;
        const int csw = c ^ ((r >> 1) & 3);
        const size_t rb = ((l < 2) ? rowA0 : rowB0) + (size_t)r;
        srcOff[l] = (unsigned int)(rb * ROW_B + (size_t)csw * 16);
        dstOff[l] = ((l < 2) ? 0 : 8192) + e * 16;
    }

    i32x4 acc[4][4];
#pragma unroll
    for (int i = 0; i < 4; ++i)
#pragma unroll
        for (int j = 0; j < 4; ++j) acc[i][j] = (i32x4){0, 0, 0, 0};

    // precomputed swizzled LDS byte offsets for fragment reads (iter-invariant)
    int aOff[4], bOff[4];
#pragma unroll
    for (int mi = 0; mi < 4; ++mi) {
        const int r = wr * 64 + mi * 16 + (lane & 15);
        aOff[mi] = r * 64 + (fc ^ ((r >> 1) & 3)) * 16;
    }
#pragma unroll
    for (int ni = 0; ni < 4; ++ni) {
        const int r = wc * 64 + ni * 16 + (lane & 15);
        bOff[ni] = 8192 + r * 64 + (fc ^ ((r >> 1) & 3)) * 16;
    }

    // prologue: stage K-tiles 0,1 into buffers 0,1
#pragma unroll
    for (int l = 0; l < 4; ++l)
        __builtin_amdgcn_global_load_lds(
            (const __attribute__((address_space(1))) void*)(xb8 + srcOff[l]),
            (__attribute__((address_space(3))) void*)(&lds[0][0] + dstOff[l]), 16, 0, 0);
#pragma unroll
    for (int l = 0; l < 4; ++l)
        __builtin_amdgcn_global_load_lds(
            (const __attribute__((address_space(1))) void*)(xb8 + srcOff[l] + 64u),
            (__attribute__((address_space(3))) void*)(&lds[1][0] + dstOff[l]), 16, 0, 0);
    asm volatile("s_waitcnt vmcnt(4)" ::: "memory");   // tile 0 landed (tile 1 in flight)
    asm volatile("s_barrier" ::: "memory");

    Frags fA, fB;
    // read tile 0 fragments into fA
#pragma unroll
    for (int mi = 0; mi < 4; ++mi) fA.a[mi] = *(const i32x4*)(&lds[0][0] + aOff[mi]);
#pragma unroll
    for (int ni = 0; ni < 4; ++ni) fA.b[ni] = *(const i32x4*)(&lds[0][0] + bOff[ni]);

    auto body = [&](int t, Frags& cur, Frags& nxt) {
        // 1. prefetch tile t+2 (buf (t+2)%3: its readers drained + barrier'd at t-1)
        if (t + 2 < NKT) {
            unsigned char* buf = &lds[(t + 2) % 3][0];
            const unsigned int kg = (unsigned int)(t + 2) * 64u;
#pragma unroll
            for (int l = 0; l < 4; ++l)
                __builtin_amdgcn_global_load_lds(
                    (const __attribute__((address_space(1))) void*)(xb8 + srcOff[l] + kg),
                    (__attribute__((address_space(3))) void*)(buf + dstOff[l]), 16, 0, 0);
        }
        // 2. drain my prior ds_reads (issued 1 iter ago) + my tile t+1 gloads
        asm volatile("s_waitcnt lgkmcnt(0)" ::: "memory");
        if (t + 2 < NKT)
            asm volatile("s_waitcnt vmcnt(4)" ::: "memory");   // counted: t+2's stay in flight
        else
            asm volatile("s_waitcnt vmcnt(0)" ::: "memory");
        // 3. all waves: tile t+1 staged, all prior reads drained
        asm volatile("s_barrier" ::: "memory");
        // 4. ds_read tile t+1 into nxt (feeds NEXT iter's MFMA -> overlaps this MFMA)
        if (t + 1 < NKT) {
            const unsigned char* buf = &lds[(t + 1) % 3][0];
#pragma unroll
            for (int mi = 0; mi < 4; ++mi) nxt.a[mi] = *(const i32x4*)(buf + aOff[mi]);
#pragma unroll
            for (int ni = 0; ni < 4; ++ni) nxt.b[ni] = *(const i32x4*)(buf + bOff[ni]);
        }
        // 5. MFMA tile t from cur (register-only, independent of step 4)
        __builtin_amdgcn_s_setprio(1);
#pragma unroll
        for (int mi = 0; mi < 4; ++mi)
#pragma unroll
            for (int ni = 0; ni < 4; ++ni)
                acc[mi][ni] = __builtin_amdgcn_mfma_i32_16x16x64_i8(
                    cur.a[mi], cur.b[ni], acc[mi][ni], 0, 0, 0);
        __builtin_amdgcn_s_setprio(0);
    };

    for (int tt = 0; tt < NKT / 2; ++tt) {
        body(2 * tt,     fA, fB);
        body(2 * tt + 1, fB, fA);
    }

    // ---- fused epilogue: exp terms + row/col partial sums ----
    const float lv  = logvar[0];
    const float var = __expf(lv) + 1e-10f;
    const float cc  = 0.5f / var;

    const int colBase = (int)rowB0 + wc * 64 + (lane & 15);
    const int rowBase = (int)rowA0 + wr * 64 + (lane >> 4) * 4;

    // row sums -> se[i]  (diagonal tile bm==bn fully computed; i==j override exact)
#pragma unroll
    for (int mi = 0; mi < 4; ++mi) {
#pragma unroll
        for (int rg = 0; rg < 4; ++rg) {
            const int i = rowBase + mi * 16 + rg;
            const float xni = xn[i];
            float rs = 0.f;
#pragma unroll
            for (int ni = 0; ni < 4; ++ni) {
                const int j = colBase + ni * 16;
                const float g = (float)acc[mi][ni][rg] * INV_S2;
                const float dist = xni + xn[j] - 2.f * g;
                rs += (i == j) ? 1.0f : __expf(-cc * fmaxf(dist, 0.f));
            }
#pragma unroll
            for (int d = 1; d < 16; d <<= 1) rs += __shfl_xor(rs, d);
            if ((lane & 15) == 0) atomicAdd(&se[i], rs);
        }
    }

    // col-mirror sums -> se[j], strictly off-diagonal tiles only (i != j always)
    if (bm != bn) {
#pragma unroll
        for (int ni = 0; ni < 4; ++ni) {
            const int j = colBase + ni * 16;
            const float xnj = xn[j];
            float cs = 0.f;
#pragma unroll
            for (int mi = 0; mi < 4; ++mi)
#pragma unroll
                for (int rg = 0; rg < 4; ++rg) {
                    const int i = rowBase + mi * 16 + rg;
                    const float g = (float)acc[mi][ni][rg] * INV_S2;
                    cs += __expf(-cc * fmaxf(xn[i] + xnj - 2.f * g, 0.f));
                }
#pragma unroll
            for (int d = 16; d < 64; d <<= 1) cs += __shfl_xor(cs, d);
            if ((lane >> 4) == 0) atomicAdd(&se[j], cs);
        }
    }
}

// ---------- kernel 3: KL scalar ----------
__global__ __launch_bounds__(256) void kl_kernel(const float* __restrict__ se,
                                                 float* __restrict__ out)
{
    const int tid = threadIdx.x;
    float s = 0.f;
    for (int i = tid; i < B_DIM; i += 256) s += logf(se[i]);
#pragma unroll
    for (int d = 32; d > 0; d >>= 1) s += __shfl_down(s, d);
    __shared__ float red[4];
    if ((tid & 63) == 0) red[tid >> 6] = s;
    __syncthreads();
    if (tid == 0) {
        const float dc = -(red[0] + red[1] + red[2] + red[3]) / (float)B_DIM;
        out[0] = (logf((float)B_DIM) + dc) / logf(2.f);
    }
}

// ---------- kernel 4 (fallback path only): x_t elementwise ----------
__global__ __launch_bounds__(256) void xt_kernel(const float4* __restrict__ x,
                                                 const float4* __restrict__ nz,
                                                 const float* __restrict__ logvar,
                                                 float4* __restrict__ out, int n4)
{
    const float sc = expf(0.5f * logvar[0]);
    for (int i = blockIdx.x * blockDim.x + threadIdx.x; i < n4;
         i += gridDim.x * blockDim.x) {
        float4 va = x[i], vb = nz[i];
        float4 o;
        o.x = fmaf(sc, vb.x, va.x);
        o.y = fmaf(sc, vb.y, va.y);
        o.z = fmaf(sc, vb.z, va.z);
        o.w = fmaf(sc, vb.w, va.w);
        out[i] = o;
    }
}

extern "C" void kernel_launch(void* const* d_in, const int* in_sizes, int n_in,
                              void* d_out, int out_size, void* d_ws, size_t ws_size,
                              hipStream_t stream)
{
    const float* x      = (const float*)d_in[0];
    const float* noise  = (const float*)d_in[1];
    const float* logvar = (const float*)d_in[2];
    float* out = (float*)d_out;

    const size_t NEL      = (size_t)B_DIM * K_DIM;      // 25165824
    const size_t XB_BYTES = (size_t)B_DIM * ROW_B;      // 25165824 B
    const int    NTILES   = NTT * (NTT + 1) / 2;        // 2080 triangular 128x128 tiles

    const bool use_ws = ws_size >= XB_BYTES + 2 * (size_t)B_DIM * sizeof(float) + 256;

    if (use_ws) {
        // xb/xn/se live in d_ws; x_t written directly by fused prep
        unsigned int* xb = (unsigned int*)d_ws;
        float* xn = (float*)((char*)d_ws + XB_BYTES);
        float* se = xn + B_DIM;

        prep_kernel<<<B_DIM, 384, 0, stream>>>(x, noise, logvar, out, xb, xn, se);
        gram_lse_kernel<<<NTILES, 256, 0, stream>>>(xb, xn, logvar, se);
        kl_kernel<<<1, 256, 0, stream>>>(se, out + NEL);
    } else {
        // fallback: scratch carved from d_out, x_t written last
        unsigned int* xb = (unsigned int*)d_out;
        float* xn = (float*)((char*)d_out + (32u << 20));
        float* se = xn + B_DIM;

        prep_kernel<<<B_DIM, 384, 0, stream>>>(x, noise, logvar, nullptr, xb, xn, se);
        gram_lse_kernel<<<NTILES, 256, 0, stream>>>(xb, xn, logvar, se);
        kl_kernel<<<1, 256, 0, stream>>>(se, out + NEL);
        xt_kernel<<<2048, 256, 0, stream>>>((const float4*)x, (const float4*)noise,
                                            logvar, (float4*)out, (int)(NEL / 4));
    }
}